// Round 6
// baseline (2957.865 us; speedup 1.0000x reference)
//
#include <hip/hip_runtime.h>
#include <math.h>

typedef unsigned int uint;
typedef unsigned short ushort;
typedef unsigned long long u64;

constexpr int B_    = 512;
constexpr int S_    = 190;
constexpr int D_    = 128;
constexpr int NDEC_ = 10;
constexpr int CN_   = 127;
constexpr int PCR_  = 63;
constexpr int MR_   = B_ * S_;  // 97280 = 1520*64 = 760*128

typedef __attribute__((ext_vector_type(4))) short bf16x4;
typedef __attribute__((ext_vector_type(8))) short bf16x8;
typedef __attribute__((ext_vector_type(4))) float f32x4;

__device__ __forceinline__ ushort f2b(float f) {
    uint x = __float_as_uint(f);
    uint r = x + 0x7fffu + ((x >> 16) & 1u);
    return (ushort)(r >> 16);
}
__device__ __forceinline__ float gelu_f(float v) {
    return 0.5f * v * (1.0f + erff(v * 0.70710678118654752f));
}
// LDS swizzles (element index)
__device__ __forceinline__ int lds_e(int s, int c)  { return s * 128 + (c ^ ((s & 7) << 3)); }  // bf16 [*][128]
__device__ __forceinline__ int pswz(int r, int c)   { return r * 512 + (c ^ ((r & 7) << 3)); }  // bf16 [64][512]
__device__ __forceinline__ int xswz(int r, int c)   { return r * 128 + (c ^ ((r & 7) << 2)); }  // f32  [64][128]

// ---------------------------------------------------------------------------
__device__ bool ablk(int i, int j, const u64* chk) {
    if (i < CN_ && j < CN_) return (i == j) || ((chk[i] & chk[j]) != 0ull);
    if (i < CN_)            return (chk[i] >> (j - CN_)) & 1ull;
    if (j < CN_)            return (chk[j] >> (i - CN_)) & 1ull;
    return i == j;
}
__global__ __launch_bounds__(256) void mbits2_k(const int* __restrict__ pc,
                                                uint* __restrict__ mb) {
    __shared__ u64 chk[CN_];
    int tid = threadIdx.x;
    if (tid < CN_) {
        u64 m = 0;
        for (int r = 0; r < PCR_; ++r)
            if (pc[r * CN_ + tid] > 0) m |= (1ull << r);
        chk[tid] = m;
    }
    __syncthreads();
    for (int idx = tid; idx < S_ * 8; idx += 256) {
        int i = idx >> 3, w = idx & 7;
        uint word = 0;
        if (w < 6)
            for (int b = 0; b < 32; ++b) {
                int j = w * 32 + b;
                if (j < S_ && ablk(i, j, chk)) word |= (1u << b);
            }
        mb[idx] = word;
    }
}

// ---------------------------------------------------------------------------
// Fused embed + entry LayerNorm (ln1_0): writes x f32 and h bf16.
__global__ __launch_bounds__(256) void embln_k(const float* __restrict__ mag,
                                               const float* __restrict__ syn,
                                               const float* __restrict__ se,
                                               const float* __restrict__ g,
                                               const float* __restrict__ bta,
                                               float* __restrict__ x,
                                               ushort* __restrict__ h) {
    int wave = threadIdx.x >> 6;
    int lane = threadIdx.x & 63;
    long row = (long)blockIdx.x * 4 + wave;
    int b = (int)(row / S_), s = (int)(row % S_);
    float e = (s < CN_) ? mag[b * CN_ + s] : syn[b * PCR_ + (s - CN_)];
    float2 sev = *(const float2*)(se + s * D_ + lane * 2);
    float vx = sev.x * e, vy = sev.y * e;
    float sum = vx + vy, sq = vx * vx + vy * vy;
    #pragma unroll
    for (int o = 32; o; o >>= 1) { sum += __shfl_xor(sum, o); sq += __shfl_xor(sq, o); }
    float mean = sum * (1.0f / D_);
    float var  = sq * (1.0f / D_) - mean * mean;
    float inv  = rsqrtf(var + 1e-5f);
    float2 gv = *(const float2*)(g + lane * 2);
    float2 bv = *(const float2*)(bta + lane * 2);
    float o0 = gv.x * (vx - mean) * inv + bv.x;
    float o1 = gv.y * (vy - mean) * inv + bv.y;
    float2 xv; xv.x = vx; xv.y = vy;
    *(float2*)(x + row * D_ + lane * 2) = xv;
    uint packed = (uint)f2b(o0) | ((uint)f2b(o1) << 16);
    *(uint*)(h + row * D_ + lane * 2) = packed;
}

// ---------------------------------------------------------------------------
// Weight transposes (setup)
__global__ void wtr_k(const float* __restrict__ src, ushort* __restrict__ dst,
                      int K, int N) {
    int idx = blockIdx.x * 256 + threadIdx.x;
    int KN = K * N;
    int l = idx / KN, rem = idx % KN;
    int n = rem / K, k = rem % K;
    dst[idx] = f2b(src[(long)l * KN + (long)k * N + n]);
}
__global__ void wtr_qkv_k(const float* __restrict__ Wq, const float* __restrict__ Wk,
                          const float* __restrict__ Wv, ushort* __restrict__ dst) {
    int idx = blockIdx.x * 256 + threadIdx.x;
    int l = idx / (384 * 128);
    int rem = idx % (384 * 128);
    int n = rem >> 7, k = rem & 127;
    const float* src = (n < 128) ? Wq : (n < 256) ? Wk : Wv;
    dst[idx] = f2b(src[l * 16384 + k * 128 + (n & 127)]);
}
__global__ void bcat_k(const float* __restrict__ bq, const float* __restrict__ bk,
                       const float* __restrict__ bv, float* __restrict__ dst) {
    int idx = blockIdx.x * 256 + threadIdx.x;
    int l = idx / 384, n = idx % 384;
    const float* s = (n < 128) ? bq : (n < 256) ? bk : bv;
    dst[idx] = s[l * 128 + (n & 127)];
}

// ---------------------------------------------------------------------------
// QKV GEMM: BM=128, BN=128 (col-block via blockIdx.y), K=128, 256 thr, 4 waves
// row-split (32 rows each). Output bf16 at stride 384.
__global__ __launch_bounds__(256) void gemm_k4(const ushort* __restrict__ A,
                                               const ushort* __restrict__ Wt,
                                               const float* __restrict__ bias,
                                               ushort* __restrict__ outp) {
    __shared__ ushort Al[128 * 128];
    __shared__ ushort Bl[128 * 128];
    const int tid = threadIdx.x;
    const int lane = tid & 63, wid = tid >> 6;
    const int lr = lane & 15, lh = lane >> 4;
    const long row0 = (long)blockIdx.x * 128;
    const int cb = blockIdx.y;
    const ushort* Wtb = Wt + cb * 128 * 128;

    #pragma unroll
    for (int i = 0; i < 8; ++i) {
        int idx = i * 256 + tid;
        int r = idx >> 4, s = idx & 15;
        uint4 d = *(const uint4*)(A + (row0 + r) * 128 + s * 8);
        *(uint4*)&Al[lds_e(r, s * 8)] = d;
        uint4 e = *(const uint4*)(Wtb + r * 128 + s * 8);
        *(uint4*)&Bl[lds_e(r, s * 8)] = e;
    }
    __syncthreads();

    f32x4 acc[2][8];
    #pragma unroll
    for (int i = 0; i < 2; ++i)
        #pragma unroll
        for (int j = 0; j < 8; ++j) { f32x4 z = {0.f,0.f,0.f,0.f}; acc[i][j] = z; }

    #pragma unroll
    for (int ks = 0; ks < 4; ++ks) {
        bf16x8 af[2], bfr[8];
        #pragma unroll
        for (int fi = 0; fi < 2; ++fi)
            af[fi] = *(const bf16x8*)&Al[lds_e((wid << 5) + (fi << 4) + lr, (ks << 5) + (lh << 3))];
        #pragma unroll
        for (int fj = 0; fj < 8; ++fj)
            bfr[fj] = *(const bf16x8*)&Bl[lds_e((fj << 4) + lr, (ks << 5) + (lh << 3))];
        #pragma unroll
        for (int fi = 0; fi < 2; ++fi)
            #pragma unroll
            for (int fj = 0; fj < 8; ++fj)
                acc[fi][fj] = __builtin_amdgcn_mfma_f32_16x16x32_bf16(af[fi], bfr[fj], acc[fi][fj], 0, 0, 0);
    }

    float bv[8];
    #pragma unroll
    for (int fj = 0; fj < 8; ++fj) bv[fj] = bias[cb * 128 + (fj << 4) + lr];
    #pragma unroll
    for (int fi = 0; fi < 2; ++fi)
        #pragma unroll
        for (int fj = 0; fj < 8; ++fj)
            #pragma unroll
            for (int rg = 0; rg < 4; ++rg) {
                long row = row0 + (wid << 5) + (fi << 4) + (lh << 2) + rg;
                outp[row * 384 + cb * 128 + (fj << 4) + lr] = f2b(acc[fi][fj][rg] + bv[fj]);
            }
}

// ---------------------------------------------------------------------------
// Attention + o-proj + residual. Block = batch b, 512 threads (8 waves = heads).
// After K/V fragment loads, LDS is reused: o tiles -> ks region, Wo -> vs region.
// o-proj: waves 0-5, 32 rows each; epilogue adds bias + x residual, writes x.
__global__ __launch_bounds__(512) void attn4_k(const ushort* __restrict__ qkv,
                                               const uint* __restrict__ mb,
                                               const ushort* __restrict__ Wot,
                                               const float* __restrict__ bo,
                                               float* __restrict__ x) {
    __shared__ ushort ks[192 * 128];
    __shared__ ushort vs[192 * 128];
    const int b = blockIdx.x, tid = threadIdx.x;
    const long base = (long)b * S_ * 384;

    for (int idx = tid; idx < S_ * 16; idx += 512) {
        int r = idx >> 4, sl = idx & 15;
        uint4 uk = *(const uint4*)(qkv + base + (long)r * 384 + 128 + sl * 8);
        uint4 uv = *(const uint4*)(qkv + base + (long)r * 384 + 256 + sl * 8);
        int w = lds_e(r, sl * 8);
        *(uint4*)&ks[w] = uk;
        *(uint4*)&vs[w] = uv;
    }
    __syncthreads();

    const int h = tid >> 6;
    const int lane = tid & 63;
    const int lr = lane & 15, lh = lane >> 4;
    const int lh2 = lh & 1;

    bf16x8 kf[12];
    #pragma unroll
    for (int jt = 0; jt < 12; ++jt) {
        int j = jt * 16 + lr; if (j > 189) j = 189;
        bf16x8 v8 = *(const bf16x8*)&ks[lds_e(j, h * 16 + lh2 * 8)];
        if (lh >= 2) { bf16x8 z = {0,0,0,0,0,0,0,0}; v8 = z; }
        kf[jt] = v8;
    }
    bf16x4 vf[12];
    #pragma unroll
    for (int jt = 0; jt < 12; ++jt) {
        int j0 = jt * 16 + lh * 4;
        int c = h * 16 + lr;
        int ja = j0 + 0 > 189 ? 189 : j0 + 0;
        int jb = j0 + 1 > 189 ? 189 : j0 + 1;
        int jc = j0 + 2 > 189 ? 189 : j0 + 2;
        int jd = j0 + 3 > 189 ? 189 : j0 + 3;
        bf16x4 v4;
        v4[0] = (short)vs[lds_e(ja, c)];
        v4[1] = (short)vs[lds_e(jb, c)];
        v4[2] = (short)vs[lds_e(jc, c)];
        v4[3] = (short)vs[lds_e(jd, c)];
        vf[jt] = v4;
    }
    __syncthreads();   // kf/vf in regs; ks/vs now reusable

    // stage Wo into vs region (swizzled [128][128])
    #pragma unroll
    for (int i = 0; i < 4; ++i) {
        int idx = i * 512 + tid;
        int r = idx >> 4, sl = idx & 15;
        uint4 d = *(const uint4*)(Wot + r * 128 + sl * 8);
        *(uint4*)&vs[lds_e(r, sl * 8)] = d;
    }

    bf16x8 qf = *(const bf16x8*)(qkv + base + (long)lr * 384 + h * 16 + lh2 * 8);

    for (int qt = 0; qt < 12; ++qt) {
        f32x4 T[12];
        f32x4 zero = {0.f, 0.f, 0.f, 0.f};
        #pragma unroll
        for (int jt = 0; jt < 12; ++jt)
            T[jt] = __builtin_amdgcn_mfma_f32_16x16x32_bf16(kf[jt], qf, zero, 0, 0, 0);
        {
            int sn = (qt + 1) * 16 + lr; if (sn > 189) sn = 189;
            qf = *(const bf16x8*)(qkv + base + (long)sn * 384 + h * 16 + lh2 * 8);
        }
        int qc = qt * 16 + lr; if (qc > 189) qc = 189;
        uint mw[6];
        #pragma unroll
        for (int w = 0; w < 6; ++w) mw[w] = mb[qc * 8 + w];

        float p[12][4];
        float lsum = 0.f;
        #pragma unroll
        for (int jt = 0; jt < 12; ++jt) {
            uint word = mw[jt >> 1];
            #pragma unroll
            for (int r = 0; r < 4; ++r) {
                int bit = ((jt & 1) << 4) + 4 * lh + r;
                float e = __expf(T[jt][r] * 0.25f);
                float pv = ((word >> bit) & 1u) ? e : 0.f;
                p[jt][r] = pv;
                lsum += pv;
            }
        }
        lsum += __shfl_xor(lsum, 16);
        lsum += __shfl_xor(lsum, 32);
        float inv = 1.0f / lsum;

        f32x4 acc = {0.f, 0.f, 0.f, 0.f};
        #pragma unroll
        for (int jt = 0; jt < 12; ++jt) {
            uint lo, hi;
            float a0 = p[jt][0] * inv, a1 = p[jt][1] * inv;
            float a2 = p[jt][2] * inv, a3 = p[jt][3] * inv;
            asm("v_cvt_pk_bf16_f32 %0, %1, %2" : "=v"(lo) : "v"(a0), "v"(a1));
            asm("v_cvt_pk_bf16_f32 %0, %1, %2" : "=v"(hi) : "v"(a2), "v"(a3));
            uint2 u; u.x = lo; u.y = hi;
            bf16x4 pf = *(bf16x4*)&u;
            asm("s_nop 1\n\tv_mfma_f32_16x16x16_bf16 %0, %1, %2, %0"
                : "+v"(acc) : "v"(pf), "v"(vf[jt]));
        }
        asm volatile("s_nop 7\n\ts_nop 7" : "+v"(acc));

        // o tile -> ks region (rows 0..191 all written; 190/191 garbage rows)
        #pragma unroll
        for (int r = 0; r < 4; ++r) {
            int qg = qt * 16 + 4 * lh + r;
            ks[lds_e(qg, h * 16 + lr)] = f2b(acc[r]);
        }
    }
    __syncthreads();   // o + Wo staged complete

    // o-proj: waves 0..5, rows [32w, 32w+32)
    if (h < 6) {
        const int w = h;
        f32x4 acc[2][8];
        #pragma unroll
        for (int i = 0; i < 2; ++i)
            #pragma unroll
            for (int j = 0; j < 8; ++j) { f32x4 z = {0.f,0.f,0.f,0.f}; acc[i][j] = z; }
        #pragma unroll
        for (int ksi = 0; ksi < 4; ++ksi) {
            bf16x8 af[2], bfr[8];
            #pragma unroll
            for (int fi = 0; fi < 2; ++fi)
                af[fi] = *(const bf16x8*)&ks[lds_e((w << 5) + (fi << 4) + lr, (ksi << 5) + (lh << 3))];
            #pragma unroll
            for (int fj = 0; fj < 8; ++fj)
                bfr[fj] = *(const bf16x8*)&vs[lds_e((fj << 4) + lr, (ksi << 5) + (lh << 3))];
            #pragma unroll
            for (int fi = 0; fi < 2; ++fi)
                #pragma unroll
                for (int fj = 0; fj < 8; ++fj)
                    acc[fi][fj] = __builtin_amdgcn_mfma_f32_16x16x32_bf16(af[fi], bfr[fj], acc[fi][fj], 0, 0, 0);
        }
        float bv[8];
        #pragma unroll
        for (int fj = 0; fj < 8; ++fj) bv[fj] = bo[(fj << 4) + lr];
        #pragma unroll
        for (int fi = 0; fi < 2; ++fi)
            #pragma unroll
            for (int rg = 0; rg < 4; ++rg) {
                int row = (w << 5) + (fi << 4) + (lh << 2) + rg;
                int rc = row > 189 ? 189 : row;
                long grow = (long)b * S_ + rc;
                #pragma unroll
                for (int fj = 0; fj < 8; ++fj) {
                    int col = (fj << 4) + lr;
                    float val = acc[fi][fj][rg] + bv[fj] + x[grow * 128 + col];
                    if (row < S_) x[grow * 128 + col] = val;
                }
            }
    }
}

// ---------------------------------------------------------------------------
// Fused FF: entry-LN (from x) -> FF1 -> GELU -> FF2 -> +residual -> exit.
// BM=64, 512 threads (8 waves). MODE 0: write x + h=LN(x;xlng). MODE 1 (layer4):
// x'=LN(x+ff;xlng=n2), write x'; h=LN(x';xlng2). MODE 2 (last): t = LN(x;enc)@finw+finb.
template <int MODE>
__global__ __launch_bounds__(512) void ffgemm_k(const float* __restrict__ xg,
                                                const ushort* __restrict__ W1t,
                                                const float* __restrict__ b1,
                                                const ushort* __restrict__ W2t,
                                                const float* __restrict__ b2,
                                                const float* __restrict__ elng,
                                                const float* __restrict__ elnb,
                                                const float* __restrict__ xlng,
                                                const float* __restrict__ xlnb,
                                                const float* __restrict__ xlng2,
                                                const float* __restrict__ xlnb2,
                                                const float* __restrict__ finw,
                                                const float* __restrict__ finb,
                                                float* __restrict__ xout,
                                                ushort* __restrict__ hout,
                                                float* __restrict__ tout) {
    __shared__ ushort Hs[64 * 128];   // 16 KB
    __shared__ float  Xs[64 * 128];   // 32 KB
    __shared__ ushort Ps[64 * 512];   // 64 KB
    __shared__ float  pL[64][2][2];
    __shared__ float  pL2[64][2][2];
    const int tid = threadIdx.x;
    const int w = tid >> 6, lane = tid & 63;
    const int lr = lane & 15, lh = lane >> 4;
    const long row0 = (long)blockIdx.x * 64;

    // ---- phase 0: load x tile, entry LN -> Hs, keep x in Xs
    {
        int r = (w << 3) + (lane >> 3);        // 0..63
        int c0 = (lane & 7) * 16;
        float v[16];
        #pragma unroll
        for (int i = 0; i < 4; ++i)
            *(float4*)&v[i * 4] = *(const float4*)(xg + (row0 + r) * 128 + c0 + i * 4);
        #pragma unroll
        for (int i = 0; i < 4; ++i)
            *(float4*)&Xs[xswz(r, c0 + i * 4)] = *(const float4*)&v[i * 4];
        float s1 = 0.f, s2 = 0.f;
        #pragma unroll
        for (int i = 0; i < 16; ++i) { s1 += v[i]; s2 += v[i] * v[i]; }
        #pragma unroll
        for (int o = 1; o < 8; o <<= 1) { s1 += __shfl_xor(s1, o); s2 += __shfl_xor(s2, o); }
        float mean = s1 * (1.0f / 128.0f);
        float var  = s2 * (1.0f / 128.0f) - mean * mean;
        float inv  = rsqrtf(var + 1e-5f);
        float g[16], bb[16];
        #pragma unroll
        for (int i = 0; i < 4; ++i) {
            *(float4*)&g[i * 4]  = *(const float4*)(elng + c0 + i * 4);
            *(float4*)&bb[i * 4] = *(const float4*)(elnb + c0 + i * 4);
        }
        uint pw[8];
        #pragma unroll
        for (int i = 0; i < 8; ++i) {
            float l0 = g[2*i]   * (v[2*i]   - mean) * inv + bb[2*i];
            float l1 = g[2*i+1] * (v[2*i+1] - mean) * inv + bb[2*i+1];
            pw[i] = (uint)f2b(l0) | ((uint)f2b(l1) << 16);
        }
        uint4 u0; u0.x = pw[0]; u0.y = pw[1]; u0.z = pw[2]; u0.w = pw[3];
        uint4 u1; u1.x = pw[4]; u1.y = pw[5]; u1.z = pw[6]; u1.w = pw[7];
        *(uint4*)&Hs[lds_e(r, c0)]     = u0;
        *(uint4*)&Hs[lds_e(r, c0 + 8)] = u1;
    }
    __syncthreads();

    // ---- phase 1: P = gelu(h @ W1 + b1), rows 32x(w>>2), pcols 128x(w&3)
    {
        const int m0 = (w >> 2) << 5;
        const int pc0 = (w & 3) << 7;
        f32x4 acc[2][8];
        #pragma unroll
        for (int i = 0; i < 2; ++i)
            #pragma unroll
            for (int j = 0; j < 8; ++j) { f32x4 z = {0.f,0.f,0.f,0.f}; acc[i][j] = z; }
        #pragma unroll
        for (int ksi = 0; ksi < 4; ++ksi) {
            bf16x8 af[2], bfr[8];
            #pragma unroll
            for (int fi = 0; fi < 2; ++fi)
                af[fi] = *(const bf16x8*)&Hs[lds_e(m0 + (fi << 4) + lr, (ksi << 5) + (lh << 3))];
            #pragma unroll
            for (int fj = 0; fj < 8; ++fj)
                bfr[fj] = *(const bf16x8*)(W1t + (long)(pc0 + (fj << 4) + lr) * 128 + (ksi << 5) + (lh << 3));
            #pragma unroll
            for (int fi = 0; fi < 2; ++fi)
                #pragma unroll
                for (int fj = 0; fj < 8; ++fj)
                    acc[fi][fj] = __builtin_amdgcn_mfma_f32_16x16x32_bf16(af[fi], bfr[fj], acc[fi][fj], 0, 0, 0);
        }
        float bv[8];
        #pragma unroll
        for (int fj = 0; fj < 8; ++fj) bv[fj] = b1[pc0 + (fj << 4) + lr];
        #pragma unroll
        for (int fi = 0; fi < 2; ++fi)
            #pragma unroll
            for (int fj = 0; fj < 8; ++fj)
                #pragma unroll
                for (int rg = 0; rg < 4; ++rg) {
                    int row = m0 + (fi << 4) + (lh << 2) + rg;
                    int pcol = pc0 + (fj << 4) + lr;
                    Ps[pswz(row, pcol)] = f2b(gelu_f(acc[fi][fj][rg] + bv[fj]));
                }
    }
    __syncthreads();

    // ---- phase 2: out = P @ W2 + b2 + x ; rows 16x(w&3), ocols 64x(w>>2)
    const int fb = w & 3, oc0 = (w >> 2) << 6;
    f32x4 acc2[4];
    #pragma unroll
    for (int j = 0; j < 4; ++j) { f32x4 z = {0.f,0.f,0.f,0.f}; acc2[j] = z; }
    #pragma unroll
    for (int ksi = 0; ksi < 16; ++ksi) {
        bf16x8 bfp = *(const bf16x8*)&Ps[pswz((fb << 4) + lr, (ksi << 5) + (lh << 3))];
        #pragma unroll
        for (int fa = 0; fa < 4; ++fa) {
            bf16x8 afw = *(const bf16x8*)(W2t + (long)(oc0 + (fa << 4) + lr) * 512 + (ksi << 5) + (lh << 3));
            acc2[fa] = __builtin_amdgcn_mfma_f32_16x16x32_bf16(afw, bfp, acc2[fa], 0, 0, 0);
        }
    }

    // ---- epilogue
    const int xrow = (fb << 4) + lr;
    const long grow = row0 + xrow;
    float vals[16];
    float s1 = 0.f, s2 = 0.f;
    #pragma unroll
    for (int fa = 0; fa < 4; ++fa)
        #pragma unroll
        for (int rg = 0; rg < 4; ++rg) {
            int col = oc0 + (fa << 4) + (lh << 2) + rg;
            float val = acc2[fa][rg] + b2[col] + Xs[xswz(xrow, col)];
            vals[fa * 4 + rg] = val;
            s1 += val; s2 += val * val;
        }
    s1 += __shfl_xor(s1, 16); s1 += __shfl_xor(s1, 32);
    s2 += __shfl_xor(s2, 16); s2 += __shfl_xor(s2, 32);
    if (lh == 0) { pL[xrow][w >> 2][0] = s1; pL[xrow][w >> 2][1] = s2; }
    __syncthreads();
    float t1 = pL[xrow][0][0] + pL[xrow][1][0];
    float t2 = pL[xrow][0][1] + pL[xrow][1][1];
    float mean = t1 * (1.0f / 128.0f);
    float var  = t2 * (1.0f / 128.0f) - mean * mean;
    float inv  = rsqrtf(var + 1e-5f);

    if (MODE == 0) {
        #pragma unroll
        for (int fa = 0; fa < 4; ++fa)
            #pragma unroll
            for (int rg = 0; rg < 4; ++rg) {
                int col = oc0 + (fa << 4) + (lh << 2) + rg;
                float val = vals[fa * 4 + rg];
                xout[grow * 128 + col] = val;
                hout[grow * 128 + col] = f2b(xlng[col] * (val - mean) * inv + xlnb[col]);
            }
    } else if (MODE == 1) {
        float xp[16], q1 = 0.f, q2 = 0.f;
        #pragma unroll
        for (int fa = 0; fa < 4; ++fa)
            #pragma unroll
            for (int rg = 0; rg < 4; ++rg) {
                int col = oc0 + (fa << 4) + (lh << 2) + rg;
                float v2 = xlng[col] * (vals[fa * 4 + rg] - mean) * inv + xlnb[col];
                xp[fa * 4 + rg] = v2;
                xout[grow * 128 + col] = v2;
                q1 += v2; q2 += v2 * v2;
            }
        q1 += __shfl_xor(q1, 16); q1 += __shfl_xor(q1, 32);
        q2 += __shfl_xor(q2, 16); q2 += __shfl_xor(q2, 32);
        if (lh == 0) { pL2[xrow][w >> 2][0] = q1; pL2[xrow][w >> 2][1] = q2; }
        __syncthreads();
        float u1 = pL2[xrow][0][0] + pL2[xrow][1][0];
        float u2 = pL2[xrow][0][1] + pL2[xrow][1][1];
        float m2 = u1 * (1.0f / 128.0f);
        float vv = u2 * (1.0f / 128.0f) - m2 * m2;
        float i2 = rsqrtf(vv + 1e-5f);
        #pragma unroll
        for (int fa = 0; fa < 4; ++fa)
            #pragma unroll
            for (int rg = 0; rg < 4; ++rg) {
                int col = oc0 + (fa << 4) + (lh << 2) + rg;
                hout[grow * 128 + col] = f2b(xlng2[col] * (xp[fa * 4 + rg] - m2) * i2 + xlnb2[col]);
            }
    } else {  // MODE 2: final enc-LN + fin dot
        float tp = 0.f;
        #pragma unroll
        for (int fa = 0; fa < 4; ++fa)
            #pragma unroll
            for (int rg = 0; rg < 4; ++rg) {
                int col = oc0 + (fa << 4) + (lh << 2) + rg;
                float lv = xlng[col] * (vals[fa * 4 + rg] - mean) * inv + xlnb[col];
                tp += lv * finw[col];
            }
        tp += __shfl_xor(tp, 16); tp += __shfl_xor(tp, 32);
        if (lh == 0) pL2[xrow][w >> 2][0] = tp;
        __syncthreads();
        if ((w >> 2) == 0 && lh == 0)
            tout[grow] = pL2[xrow][0][0] + pL2[xrow][1][0] + finb[0];
    }
}

// ---------------------------------------------------------------------------
__global__ __launch_bounds__(128) void outgemm_k(const float* __restrict__ t,
                                                 const float* __restrict__ ow,
                                                 const float* __restrict__ ob,
                                                 float* __restrict__ out) {
    __shared__ float ts[S_];
    int b = blockIdx.x, tid = threadIdx.x;
    for (int i = tid; i < S_; i += 128) ts[i] = t[(long)b * S_ + i];
    __syncthreads();
    if (tid < CN_) {
        float acc = ob[tid];
        for (int s = 0; s < S_; ++s) acc = fmaf(ts[s], ow[s * CN_ + tid], acc);
        out[(long)b * CN_ + tid] = acc;
    }
}

// ---------------------------------------------------------------------------
extern "C" void kernel_launch(void* const* d_in, const int* in_sizes, int n_in,
                              void* d_out, int out_size, void* d_ws, size_t ws_size,
                              hipStream_t stream) {
    const float* mag  = (const float*)d_in[0];
    const float* syn  = (const float*)d_in[1];
    const int*   pc   = (const int*)  d_in[2];
    const float* se   = (const float*)d_in[3];
    const float* Wq   = (const float*)d_in[4];
    const float* bq   = (const float*)d_in[5];
    const float* Wk   = (const float*)d_in[6];
    const float* bk   = (const float*)d_in[7];
    const float* Wv   = (const float*)d_in[8];
    const float* bv   = (const float*)d_in[9];
    const float* Wo   = (const float*)d_in[10];
    const float* bo   = (const float*)d_in[11];
    const float* W1   = (const float*)d_in[12];
    const float* b1   = (const float*)d_in[13];
    const float* W2   = (const float*)d_in[14];
    const float* b2   = (const float*)d_in[15];
    const float* ln1g = (const float*)d_in[16];
    const float* ln1b = (const float*)d_in[17];
    const float* ln2g = (const float*)d_in[18];
    const float* ln2b = (const float*)d_in[19];
    const float* encg = (const float*)d_in[20];
    const float* encb = (const float*)d_in[21];
    const float* n2g  = (const float*)d_in[22];
    const float* n2b  = (const float*)d_in[23];
    const float* finw = (const float*)d_in[24];
    const float* finb = (const float*)d_in[25];
    const float* outw = (const float*)d_in[26];
    const float* outb = (const float*)d_in[27];
    float* out = (float*)d_out;

    // Workspace (bytes): x 49.8MB | h 24.9MB | qkv 74.7MB | weights | mb | t
    char* p = (char*)d_ws;
    float*  x     = (float*) p;                      // [MR][128] f32
    ushort* h     = (ushort*)(p + 49807360);         // [MR][128] bf16
    ushort* qkv   = (ushort*)(p + 74711040);         // [MR][384] bf16
    ushort* Wqkvt = (ushort*)(p + 149422080);        // [10][384][128]
    ushort* Wot   = (ushort*)(p + 150405120);        // [10][128][128]
    ushort* W1t   = (ushort*)(p + 150732800);        // [10][512][128]
    ushort* W2t   = (ushort*)(p + 152043520);        // [10][128][512]
    float*  bqkv  = (float*) (p + 153354240);        // [10][384]
    uint*   mb    = (uint*)  (p + 153369600);        // [190][8]
    float*  t     = (float*) (p + 153375680);        // [MR]

    mbits2_k<<<1, 256, 0, stream>>>(pc, mb);
    wtr_qkv_k<<<1920, 256, 0, stream>>>(Wq, Wk, Wv, Wqkvt);
    wtr_k<<<640, 256, 0, stream>>>(Wo, Wot, 128, 128);
    wtr_k<<<2560, 256, 0, stream>>>(W1, W1t, 128, 512);
    wtr_k<<<2560, 256, 0, stream>>>(W2, W2t, 512, 128);
    bcat_k<<<15, 256, 0, stream>>>(bq, bk, bv, bqkv);
    embln_k<<<MR_ / 4, 256, 0, stream>>>(mag, syn, se, ln1g, ln1b, x, h);

    for (int i = 0; i < NDEC_; ++i) {
        gemm_k4<<<dim3(760, 3), 256, 0, stream>>>(
            h, Wqkvt + (long)i * 49152, bqkv + i * 384, qkv);
        attn4_k<<<B_, 512, 0, stream>>>(qkv, mb, Wot + (long)i * 16384, bo + i * 128, x);
        const ushort* w1 = W1t + (long)i * 65536;
        const ushort* w2 = W2t + (long)i * 65536;
        const float* bb1 = b1 + i * 512;
        const float* bb2 = b2 + i * 128;
        const float* eg = ln2g + i * 128, *eb = ln2b + i * 128;
        if (i == 4) {
            ffgemm_k<1><<<1520, 512, 0, stream>>>(
                x, w1, bb1, w2, bb2, eg, eb, n2g, n2b,
                ln1g + 5 * 128, ln1b + 5 * 128, nullptr, nullptr, x, h, nullptr);
        } else if (i == NDEC_ - 1) {
            ffgemm_k<2><<<1520, 512, 0, stream>>>(
                x, w1, bb1, w2, bb2, eg, eb, encg, encb,
                nullptr, nullptr, finw, finb, nullptr, nullptr, t);
        } else {
            ffgemm_k<0><<<1520, 512, 0, stream>>>(
                x, w1, bb1, w2, bb2, eg, eb, ln1g + (i + 1) * 128, ln1b + (i + 1) * 128,
                nullptr, nullptr, nullptr, nullptr, x, h, nullptr);
        }
    }

    outgemm_k<<<B_, 128, 0, stream>>>(t, outw, outb, out);
}

// Round 7
// 2146.846 us; speedup vs baseline: 1.3778x; 1.3778x over previous
//
#include <hip/hip_runtime.h>
#include <math.h>

typedef unsigned int uint;
typedef unsigned short ushort;
typedef unsigned long long u64;

constexpr int B_    = 512;
constexpr int S_    = 190;
constexpr int D_    = 128;
constexpr int NDEC_ = 10;
constexpr int CN_   = 127;
constexpr int PCR_  = 63;
constexpr int MR_   = B_ * S_;  // 97280 = 760*128

typedef __attribute__((ext_vector_type(4))) short bf16x4;
typedef __attribute__((ext_vector_type(8))) short bf16x8;
typedef __attribute__((ext_vector_type(4))) float f32x4;

__device__ __forceinline__ ushort f2b(float f) {
    uint x = __float_as_uint(f);
    uint r = x + 0x7fffu + ((x >> 16) & 1u);
    return (ushort)(r >> 16);
}
__device__ __forceinline__ float gelu_f(float v) {
    return 0.5f * v * (1.0f + erff(v * 0.70710678118654752f));
}
__device__ __forceinline__ int lds_e(int s, int c) { return s * 128 + (c ^ ((s & 7) << 3)); }

// ---------------------------------------------------------------------------
__device__ bool ablk(int i, int j, const u64* chk) {
    if (i < CN_ && j < CN_) return (i == j) || ((chk[i] & chk[j]) != 0ull);
    if (i < CN_)            return (chk[i] >> (j - CN_)) & 1ull;
    if (j < CN_)            return (chk[j] >> (i - CN_)) & 1ull;
    return i == j;
}
__global__ __launch_bounds__(256) void mbits2_k(const int* __restrict__ pc,
                                                uint* __restrict__ mb) {
    __shared__ u64 chk[CN_];
    int tid = threadIdx.x;
    if (tid < CN_) {
        u64 m = 0;
        for (int r = 0; r < PCR_; ++r)
            if (pc[r * CN_ + tid] > 0) m |= (1ull << r);
        chk[tid] = m;
    }
    __syncthreads();
    for (int idx = tid; idx < S_ * 8; idx += 256) {
        int i = idx >> 3, w = idx & 7;
        uint word = 0;
        if (w < 6)
            for (int b = 0; b < 32; ++b) {
                int j = w * 32 + b;
                if (j < S_ && ablk(i, j, chk)) word |= (1u << b);
            }
        mb[idx] = word;
    }
}

// ---------------------------------------------------------------------------
// Fused embed + entry LayerNorm (ln1_0): writes x f32 and h bf16.
__global__ __launch_bounds__(256) void embln_k(const float* __restrict__ mag,
                                               const float* __restrict__ syn,
                                               const float* __restrict__ se,
                                               const float* __restrict__ g,
                                               const float* __restrict__ bta,
                                               float* __restrict__ x,
                                               ushort* __restrict__ h) {
    int wave = threadIdx.x >> 6;
    int lane = threadIdx.x & 63;
    long row = (long)blockIdx.x * 4 + wave;
    int b = (int)(row / S_), s = (int)(row % S_);
    float e = (s < CN_) ? mag[b * CN_ + s] : syn[b * PCR_ + (s - CN_)];
    float2 sev = *(const float2*)(se + s * D_ + lane * 2);
    float vx = sev.x * e, vy = sev.y * e;
    float sum = vx + vy, sq = vx * vx + vy * vy;
    #pragma unroll
    for (int o = 32; o; o >>= 1) { sum += __shfl_xor(sum, o); sq += __shfl_xor(sq, o); }
    float mean = sum * (1.0f / D_);
    float var  = sq * (1.0f / D_) - mean * mean;
    float inv  = rsqrtf(var + 1e-5f);
    float2 gv = *(const float2*)(g + lane * 2);
    float2 bv = *(const float2*)(bta + lane * 2);
    float o0 = gv.x * (vx - mean) * inv + bv.x;
    float o1 = gv.y * (vy - mean) * inv + bv.y;
    float2 xv; xv.x = vx; xv.y = vy;
    *(float2*)(x + row * D_ + lane * 2) = xv;
    uint packed = (uint)f2b(o0) | ((uint)f2b(o1) << 16);
    *(uint*)(h + row * D_ + lane * 2) = packed;
}

// ---------------------------------------------------------------------------
// Weight transposes (setup)
__global__ void wtr_k(const float* __restrict__ src, ushort* __restrict__ dst,
                      int K, int N) {
    int idx = blockIdx.x * 256 + threadIdx.x;
    int KN = K * N;
    int l = idx / KN, rem = idx % KN;
    int n = rem / K, k = rem % K;
    dst[idx] = f2b(src[(long)l * KN + (long)k * N + n]);
}
__global__ void wtr_qkv_k(const float* __restrict__ Wq, const float* __restrict__ Wk,
                          const float* __restrict__ Wv, ushort* __restrict__ dst) {
    int idx = blockIdx.x * 256 + threadIdx.x;
    int l = idx / (384 * 128);
    int rem = idx % (384 * 128);
    int n = rem >> 7, k = rem & 127;
    const float* src = (n < 128) ? Wq : (n < 256) ? Wk : Wv;
    dst[idx] = f2b(src[l * 16384 + k * 128 + (n & 127)]);
}
__global__ void bcat_k(const float* __restrict__ bq, const float* __restrict__ bk,
                       const float* __restrict__ bv, float* __restrict__ dst) {
    int idx = blockIdx.x * 256 + threadIdx.x;
    int l = idx / 384, n = idx % 384;
    const float* s = (n < 128) ? bq : (n < 256) ? bk : bv;
    dst[idx] = s[l * 128 + (n & 127)];
}

// ---------------------------------------------------------------------------
// LayerNorm standalone (layer-4 double-LN path only).
__global__ __launch_bounds__(256) void ln_k(const float* __restrict__ in,
                                            const float* __restrict__ g,
                                            const float* __restrict__ bta,
                                            ushort* __restrict__ outp) {
    int wave = threadIdx.x >> 6;
    int lane = threadIdx.x & 63;
    long row = (long)blockIdx.x * 4 + wave;
    const float* r = in + row * D_;
    float2 v = *(const float2*)(r + lane * 2);
    float sum = v.x + v.y;
    float sq  = v.x * v.x + v.y * v.y;
    #pragma unroll
    for (int o = 32; o; o >>= 1) { sum += __shfl_xor(sum, o); sq += __shfl_xor(sq, o); }
    float mean = sum * (1.0f / D_);
    float var  = sq * (1.0f / D_) - mean * mean;
    float inv  = rsqrtf(var + 1e-5f);
    float2 gv = *(const float2*)(g + lane * 2);
    float2 bv = *(const float2*)(bta + lane * 2);
    float o0 = gv.x * (v.x - mean) * inv + bv.x;
    float o1 = gv.y * (v.y - mean) * inv + bv.y;
    uint packed = (uint)f2b(o0) | ((uint)f2b(o1) << 16);
    *(uint*)(outp + row * D_ + lane * 2) = packed;
}

// ---------------------------------------------------------------------------
// Single-K-iteration GEMM: BM=128, BN=128 col-block (blockIdx.y), K=128.
// 256 thr, 4 waves row-split. Output bf16 at stride Nstride. GELU optional.
template <bool GELU>
__global__ __launch_bounds__(256) void gemm_k4(const ushort* __restrict__ A,
                                               const ushort* __restrict__ Wt,
                                               const float* __restrict__ bias,
                                               ushort* __restrict__ outp,
                                               int Nstride) {
    __shared__ ushort Al[128 * 128];
    __shared__ ushort Bl[128 * 128];
    const int tid = threadIdx.x;
    const int lane = tid & 63, wid = tid >> 6;
    const int lr = lane & 15, lh = lane >> 4;
    const long row0 = (long)blockIdx.x * 128;
    const int cb = blockIdx.y;
    const ushort* Wtb = Wt + cb * 128 * 128;

    #pragma unroll
    for (int i = 0; i < 8; ++i) {
        int idx = i * 256 + tid;
        int r = idx >> 4, s = idx & 15;
        uint4 d = *(const uint4*)(A + (row0 + r) * 128 + s * 8);
        *(uint4*)&Al[lds_e(r, s * 8)] = d;
        uint4 e = *(const uint4*)(Wtb + r * 128 + s * 8);
        *(uint4*)&Bl[lds_e(r, s * 8)] = e;
    }
    __syncthreads();

    f32x4 acc[2][8];
    #pragma unroll
    for (int i = 0; i < 2; ++i)
        #pragma unroll
        for (int j = 0; j < 8; ++j) { f32x4 z = {0.f,0.f,0.f,0.f}; acc[i][j] = z; }

    #pragma unroll
    for (int ks = 0; ks < 4; ++ks) {
        bf16x8 af[2], bfr[8];
        #pragma unroll
        for (int fi = 0; fi < 2; ++fi)
            af[fi] = *(const bf16x8*)&Al[lds_e((wid << 5) + (fi << 4) + lr, (ks << 5) + (lh << 3))];
        #pragma unroll
        for (int fj = 0; fj < 8; ++fj)
            bfr[fj] = *(const bf16x8*)&Bl[lds_e((fj << 4) + lr, (ks << 5) + (lh << 3))];
        #pragma unroll
        for (int fi = 0; fi < 2; ++fi)
            #pragma unroll
            for (int fj = 0; fj < 8; ++fj)
                acc[fi][fj] = __builtin_amdgcn_mfma_f32_16x16x32_bf16(af[fi], bfr[fj], acc[fi][fj], 0, 0, 0);
    }

    float bv[8];
    #pragma unroll
    for (int fj = 0; fj < 8; ++fj) bv[fj] = bias[cb * 128 + (fj << 4) + lr];
    #pragma unroll
    for (int fi = 0; fi < 2; ++fi)
        #pragma unroll
        for (int fj = 0; fj < 8; ++fj)
            #pragma unroll
            for (int rg = 0; rg < 4; ++rg) {
                long row = row0 + (wid << 5) + (fi << 4) + (lh << 2) + rg;
                float val = acc[fi][fj][rg] + bv[fj];
                if (GELU) val = gelu_f(val);
                outp[row * Nstride + cb * 128 + (fj << 4) + lr] = f2b(val);
            }
}

// ---------------------------------------------------------------------------
// FF2 GEMM: BN=128 full-row, K loop, fused {bias, +res->x, LayerNorm->h}.
// LNMODE: 0 = write x only; 1 = x f32 + h bf16 = LN(x); 2 = x = LN(x+ff) (norm2).
template <int LNMODE>
__global__ __launch_bounds__(256) void gemm_k3(const ushort* __restrict__ A,
                                               const ushort* __restrict__ Wt,
                                               const float* __restrict__ bias,
                                               const float* __restrict__ res,
                                               float* __restrict__ xout,
                                               ushort* __restrict__ hout,
                                               const float* __restrict__ lng,
                                               const float* __restrict__ lnb,
                                               int K) {
    __shared__ ushort Al[128 * 128];
    __shared__ ushort Bl[128 * 128];
    const int tid = threadIdx.x;
    const int lane = tid & 63, wid = tid >> 6;
    const int lr = lane & 15, lh = lane >> 4;
    const long row0 = (long)blockIdx.x * 128;

    f32x4 acc[2][8];
    #pragma unroll
    for (int i = 0; i < 2; ++i)
        #pragma unroll
        for (int j = 0; j < 8; ++j) { f32x4 z = {0.f, 0.f, 0.f, 0.f}; acc[i][j] = z; }

    for (int k0 = 0; k0 < K; k0 += 128) {
        #pragma unroll
        for (int i = 0; i < 8; ++i) {
            int idx = i * 256 + tid;
            int r = idx >> 4, s = idx & 15;
            uint4 d = *(const uint4*)(A + (row0 + r) * (long)K + k0 + s * 8);
            *(uint4*)&Al[lds_e(r, s * 8)] = d;
            uint4 e = *(const uint4*)(Wt + r * (long)K + k0 + s * 8);
            *(uint4*)&Bl[lds_e(r, s * 8)] = e;
        }
        __syncthreads();
        #pragma unroll
        for (int ks = 0; ks < 4; ++ks) {
            bf16x8 af[2], bfr[8];
            #pragma unroll
            for (int fi = 0; fi < 2; ++fi)
                af[fi] = *(const bf16x8*)&Al[lds_e((wid << 5) + (fi << 4) + lr, (ks << 5) + (lh << 3))];
            #pragma unroll
            for (int fj = 0; fj < 8; ++fj)
                bfr[fj] = *(const bf16x8*)&Bl[lds_e((fj << 4) + lr, (ks << 5) + (lh << 3))];
            #pragma unroll
            for (int fi = 0; fi < 2; ++fi)
                #pragma unroll
                for (int fj = 0; fj < 8; ++fj)
                    acc[fi][fj] = __builtin_amdgcn_mfma_f32_16x16x32_bf16(af[fi], bfr[fj], acc[fi][fj], 0, 0, 0);
        }
        __syncthreads();
    }

    #pragma unroll
    for (int fi = 0; fi < 2; ++fi) {
        #pragma unroll
        for (int rg = 0; rg < 4; ++rg) {
            long row = row0 + (wid << 5) + (fi << 4) + (lh << 2) + rg;
            float v[8], s1 = 0.f, s2 = 0.f;
            #pragma unroll
            for (int fj = 0; fj < 8; ++fj) {
                int col = (fj << 4) + lr;
                float val = acc[fi][fj][rg] + bias[col] + res[row * 128 + col];
                v[fj] = val; s1 += val; s2 += val * val;
            }
            if (LNMODE == 0) {
                #pragma unroll
                for (int fj = 0; fj < 8; ++fj)
                    xout[row * 128 + ((fj << 4) + lr)] = v[fj];
            } else {
                #pragma unroll
                for (int o = 1; o < 16; o <<= 1) {
                    s1 += __shfl_xor(s1, o);
                    s2 += __shfl_xor(s2, o);
                }
                float mean = s1 * (1.0f / 128.0f);
                float var  = s2 * (1.0f / 128.0f) - mean * mean;
                float inv  = rsqrtf(var + 1e-5f);
                #pragma unroll
                for (int fj = 0; fj < 8; ++fj) {
                    int col = (fj << 4) + lr;
                    float ln = lng[col] * (v[fj] - mean) * inv + lnb[col];
                    if (LNMODE == 1) {
                        xout[row * 128 + col] = v[fj];
                        hout[row * 128 + col] = f2b(ln);
                    } else {
                        xout[row * 128 + col] = ln;
                    }
                }
            }
        }
    }
}

// ---------------------------------------------------------------------------
// Attention + o-proj + residual + ln2 -> h. Block = batch b, 512 threads.
__global__ __launch_bounds__(512) void attn4_k(const ushort* __restrict__ qkv,
                                               const uint* __restrict__ mb,
                                               const ushort* __restrict__ Wot,
                                               const float* __restrict__ bo,
                                               const float* __restrict__ lng,
                                               const float* __restrict__ lnb,
                                               float* __restrict__ x,
                                               ushort* __restrict__ hbuf) {
    __shared__ ushort ks[192 * 128];
    __shared__ ushort vs[192 * 128];
    const int b = blockIdx.x, tid = threadIdx.x;
    const long base = (long)b * S_ * 384;

    for (int idx = tid; idx < S_ * 16; idx += 512) {
        int r = idx >> 4, sl = idx & 15;
        uint4 uk = *(const uint4*)(qkv + base + (long)r * 384 + 128 + sl * 8);
        uint4 uv = *(const uint4*)(qkv + base + (long)r * 384 + 256 + sl * 8);
        int w = lds_e(r, sl * 8);
        *(uint4*)&ks[w] = uk;
        *(uint4*)&vs[w] = uv;
    }
    __syncthreads();

    const int h = tid >> 6;
    const int lane = tid & 63;
    const int lr = lane & 15, lh = lane >> 4;
    const int lh2 = lh & 1;

    bf16x8 kf[12];
    #pragma unroll
    for (int jt = 0; jt < 12; ++jt) {
        int j = jt * 16 + lr; if (j > 189) j = 189;
        bf16x8 v8 = *(const bf16x8*)&ks[lds_e(j, h * 16 + lh2 * 8)];
        if (lh >= 2) { bf16x8 z = {0,0,0,0,0,0,0,0}; v8 = z; }
        kf[jt] = v8;
    }
    bf16x4 vf[12];
    #pragma unroll
    for (int jt = 0; jt < 12; ++jt) {
        int j0 = jt * 16 + lh * 4;
        int c = h * 16 + lr;
        int ja = j0 + 0 > 189 ? 189 : j0 + 0;
        int jb = j0 + 1 > 189 ? 189 : j0 + 1;
        int jc = j0 + 2 > 189 ? 189 : j0 + 2;
        int jd = j0 + 3 > 189 ? 189 : j0 + 3;
        bf16x4 v4;
        v4[0] = (short)vs[lds_e(ja, c)];
        v4[1] = (short)vs[lds_e(jb, c)];
        v4[2] = (short)vs[lds_e(jc, c)];
        v4[3] = (short)vs[lds_e(jd, c)];
        vf[jt] = v4;
    }
    __syncthreads();

    // stage Wo into vs region
    #pragma unroll
    for (int i = 0; i < 4; ++i) {
        int idx = i * 512 + tid;
        int r = idx >> 4, sl = idx & 15;
        uint4 d = *(const uint4*)(Wot + r * 128 + sl * 8);
        *(uint4*)&vs[lds_e(r, sl * 8)] = d;
    }

    bf16x8 qf = *(const bf16x8*)(qkv + base + (long)lr * 384 + h * 16 + lh2 * 8);

    for (int qt = 0; qt < 12; ++qt) {
        f32x4 T[12];
        f32x4 zero = {0.f, 0.f, 0.f, 0.f};
        #pragma unroll
        for (int jt = 0; jt < 12; ++jt)
            T[jt] = __builtin_amdgcn_mfma_f32_16x16x32_bf16(kf[jt], qf, zero, 0, 0, 0);
        {
            int sn = (qt + 1) * 16 + lr; if (sn > 189) sn = 189;
            qf = *(const bf16x8*)(qkv + base + (long)sn * 384 + h * 16 + lh2 * 8);
        }
        int qc = qt * 16 + lr; if (qc > 189) qc = 189;
        uint mw[6];
        #pragma unroll
        for (int w = 0; w < 6; ++w) mw[w] = mb[qc * 8 + w];

        float p[12][4];
        float lsum = 0.f;
        #pragma unroll
        for (int jt = 0; jt < 12; ++jt) {
            uint word = mw[jt >> 1];
            #pragma unroll
            for (int r = 0; r < 4; ++r) {
                int bit = ((jt & 1) << 4) + 4 * lh + r;
                float e = __expf(T[jt][r] * 0.25f);
                float pv = ((word >> bit) & 1u) ? e : 0.f;
                p[jt][r] = pv;
                lsum += pv;
            }
        }
        lsum += __shfl_xor(lsum, 16);
        lsum += __shfl_xor(lsum, 32);
        float inv = 1.0f / lsum;

        f32x4 acc = {0.f, 0.f, 0.f, 0.f};
        #pragma unroll
        for (int jt = 0; jt < 12; ++jt) {
            uint lo, hi;
            float a0 = p[jt][0] * inv, a1 = p[jt][1] * inv;
            float a2 = p[jt][2] * inv, a3 = p[jt][3] * inv;
            asm("v_cvt_pk_bf16_f32 %0, %1, %2" : "=v"(lo) : "v"(a0), "v"(a1));
            asm("v_cvt_pk_bf16_f32 %0, %1, %2" : "=v"(hi) : "v"(a2), "v"(a3));
            uint2 u; u.x = lo; u.y = hi;
            bf16x4 pf = *(bf16x4*)&u;
            asm("s_nop 1\n\tv_mfma_f32_16x16x16_bf16 %0, %1, %2, %0"
                : "+v"(acc) : "v"(pf), "v"(vf[jt]));
        }
        asm volatile("s_nop 7\n\ts_nop 7" : "+v"(acc));

        #pragma unroll
        for (int r = 0; r < 4; ++r) {
            int qg = qt * 16 + 4 * lh + r;
            ks[lds_e(qg, h * 16 + lr)] = f2b(acc[r]);
        }
    }
    __syncthreads();

    // o-proj + residual + ln2: waves 0..5, rows [32w, 32w+32)
    if (h < 6) {
        const int w = h;
        f32x4 acc[2][8];
        #pragma unroll
        for (int i = 0; i < 2; ++i)
            #pragma unroll
            for (int j = 0; j < 8; ++j) { f32x4 z = {0.f,0.f,0.f,0.f}; acc[i][j] = z; }
        #pragma unroll
        for (int ksi = 0; ksi < 4; ++ksi) {
            bf16x8 af[2], bfr[8];
            #pragma unroll
            for (int fi = 0; fi < 2; ++fi)
                af[fi] = *(const bf16x8*)&ks[lds_e((w << 5) + (fi << 4) + lr, (ksi << 5) + (lh << 3))];
            #pragma unroll
            for (int fj = 0; fj < 8; ++fj)
                bfr[fj] = *(const bf16x8*)&vs[lds_e((fj << 4) + lr, (ksi << 5) + (lh << 3))];
            #pragma unroll
            for (int fi = 0; fi < 2; ++fi)
                #pragma unroll
                for (int fj = 0; fj < 8; ++fj)
                    acc[fi][fj] = __builtin_amdgcn_mfma_f32_16x16x32_bf16(af[fi], bfr[fj], acc[fi][fj], 0, 0, 0);
        }
        float bv[8], gv[8], bb[8];
        #pragma unroll
        for (int fj = 0; fj < 8; ++fj) {
            int col = (fj << 4) + lr;
            bv[fj] = bo[col]; gv[fj] = lng[col]; bb[fj] = lnb[col];
        }
        #pragma unroll
        for (int fi = 0; fi < 2; ++fi)
            #pragma unroll
            for (int rg = 0; rg < 4; ++rg) {
                int row = (w << 5) + (fi << 4) + (lh << 2) + rg;
                int rc = row > 189 ? 189 : row;
                long grow = (long)b * S_ + rc;
                float v[8], s1 = 0.f, s2 = 0.f;
                #pragma unroll
                for (int fj = 0; fj < 8; ++fj) {
                    int col = (fj << 4) + lr;
                    float val = acc[fi][fj][rg] + bv[fj] + x[grow * 128 + col];
                    v[fj] = val; s1 += val; s2 += val * val;
                }
                #pragma unroll
                for (int o = 1; o < 16; o <<= 1) {
                    s1 += __shfl_xor(s1, o);
                    s2 += __shfl_xor(s2, o);
                }
                float mean = s1 * (1.0f / 128.0f);
                float var  = s2 * (1.0f / 128.0f) - mean * mean;
                float inv  = rsqrtf(var + 1e-5f);
                if (row < S_) {
                    #pragma unroll
                    for (int fj = 0; fj < 8; ++fj) {
                        int col = (fj << 4) + lr;
                        x[grow * 128 + col] = v[fj];
                        hbuf[grow * 128 + col] = f2b(gv[fj] * (v[fj] - mean) * inv + bb[fj]);
                    }
                }
            }
    }
}

// ---------------------------------------------------------------------------
__global__ __launch_bounds__(256) void fin_k(const float* __restrict__ x,
                                             const float* __restrict__ g,
                                             const float* __restrict__ bta,
                                             const float* __restrict__ fw,
                                             const float* __restrict__ fb,
                                             float* __restrict__ t) {
    int wave = threadIdx.x >> 6;
    int lane = threadIdx.x & 63;
    long row = (long)blockIdx.x * 4 + wave;
    const float* r = x + row * D_;
    float2 v = *(const float2*)(r + lane * 2);
    float sum = v.x + v.y;
    float sq  = v.x * v.x + v.y * v.y;
    #pragma unroll
    for (int o = 32; o; o >>= 1) { sum += __shfl_xor(sum, o); sq += __shfl_xor(sq, o); }
    float mean = sum * (1.0f / D_);
    float var  = sq * (1.0f / D_) - mean * mean;
    float inv  = rsqrtf(var + 1e-5f);
    float2 gv = *(const float2*)(g + lane * 2);
    float2 bv = *(const float2*)(bta + lane * 2);
    float y0 = gv.x * (v.x - mean) * inv + bv.x;
    float y1 = gv.y * (v.y - mean) * inv + bv.y;
    float part = y0 * fw[lane * 2] + y1 * fw[lane * 2 + 1];
    #pragma unroll
    for (int o = 32; o; o >>= 1) part += __shfl_xor(part, o);
    if (lane == 0) t[row] = part + fb[0];
}

__global__ __launch_bounds__(128) void outgemm_k(const float* __restrict__ t,
                                                 const float* __restrict__ ow,
                                                 const float* __restrict__ ob,
                                                 float* __restrict__ out) {
    __shared__ float ts[S_];
    int b = blockIdx.x, tid = threadIdx.x;
    for (int i = tid; i < S_; i += 128) ts[i] = t[(long)b * S_ + i];
    __syncthreads();
    if (tid < CN_) {
        float acc = ob[tid];
        for (int s = 0; s < S_; ++s) acc = fmaf(ts[s], ow[s * CN_ + tid], acc);
        out[(long)b * CN_ + tid] = acc;
    }
}

// ---------------------------------------------------------------------------
extern "C" void kernel_launch(void* const* d_in, const int* in_sizes, int n_in,
                              void* d_out, int out_size, void* d_ws, size_t ws_size,
                              hipStream_t stream) {
    const float* mag  = (const float*)d_in[0];
    const float* syn  = (const float*)d_in[1];
    const int*   pc   = (const int*)  d_in[2];
    const float* se   = (const float*)d_in[3];
    const float* Wq   = (const float*)d_in[4];
    const float* bq   = (const float*)d_in[5];
    const float* Wk   = (const float*)d_in[6];
    const float* bk   = (const float*)d_in[7];
    const float* Wv   = (const float*)d_in[8];
    const float* bv   = (const float*)d_in[9];
    const float* Wo   = (const float*)d_in[10];
    const float* bo   = (const float*)d_in[11];
    const float* W1   = (const float*)d_in[12];
    const float* b1   = (const float*)d_in[13];
    const float* W2   = (const float*)d_in[14];
    const float* b2   = (const float*)d_in[15];
    const float* ln1g = (const float*)d_in[16];
    const float* ln1b = (const float*)d_in[17];
    const float* ln2g = (const float*)d_in[18];
    const float* ln2b = (const float*)d_in[19];
    const float* encg = (const float*)d_in[20];
    const float* encb = (const float*)d_in[21];
    const float* n2g  = (const float*)d_in[22];
    const float* n2b  = (const float*)d_in[23];
    const float* finw = (const float*)d_in[24];
    const float* finb = (const float*)d_in[25];
    const float* outw = (const float*)d_in[26];
    const float* outb = (const float*)d_in[27];
    float* out = (float*)d_out;

    // Workspace layout (round-5 proven offsets; qkv/ff1 share 99.6MB region)
    char* p = (char*)d_ws;
    float*  x     = (float*) p;                      // [MR][128] f32
    ushort* h     = (ushort*)(p + 49807360);         // [MR][128] bf16
    ushort* qkv   = (ushort*)(p + 74711040);         // [MR][384] bf16 / ff1 [MR][512]
    ushort* Wqkvt = (ushort*)(p + 174325760);        // [10][384][128]
    ushort* Wot   = (ushort*)(p + 175308800);        // [10][128][128]
    ushort* W1t   = (ushort*)(p + 175636480);        // [10][512][128]
    ushort* W2t   = (ushort*)(p + 176947200);        // [10][128][512]
    float*  bqkv  = (float*) (p + 178257920);        // [10][384]
    uint*   mb    = (uint*)  (p + 178273280);        // [190][8]
    float*  t     = (float*) (p + 178279360);        // [MR]
    ushort* ff1   = qkv;

    mbits2_k<<<1, 256, 0, stream>>>(pc, mb);
    wtr_qkv_k<<<1920, 256, 0, stream>>>(Wq, Wk, Wv, Wqkvt);
    wtr_k<<<640, 256, 0, stream>>>(Wo, Wot, 128, 128);
    wtr_k<<<2560, 256, 0, stream>>>(W1, W1t, 128, 512);
    wtr_k<<<2560, 256, 0, stream>>>(W2, W2t, 512, 128);
    bcat_k<<<15, 256, 0, stream>>>(bq, bk, bv, bqkv);
    embln_k<<<MR_ / 4, 256, 0, stream>>>(mag, syn, se, ln1g, ln1b, x, h);

    for (int i = 0; i < NDEC_; ++i) {
        gemm_k4<false><<<dim3(760, 3), 256, 0, stream>>>(
            h, Wqkvt + (long)i * 49152, bqkv + i * 384, qkv, 384);
        attn4_k<<<B_, 512, 0, stream>>>(
            qkv, mb, Wot + (long)i * 16384, bo + i * 128,
            ln2g + i * 128, ln2b + i * 128, x, h);
        gemm_k4<true><<<dim3(760, 4), 256, 0, stream>>>(
            h, W1t + (long)i * 65536, b1 + i * 512, ff1, 512);
        if (i == 4) {
            gemm_k3<2><<<760, 256, 0, stream>>>(
                ff1, W2t + (long)i * 65536, b2 + i * 128, x, x, nullptr,
                n2g, n2b, 512);
            ln_k<<<MR_ / 4, 256, 0, stream>>>(x, ln1g + 5 * 128, ln1b + 5 * 128, h);
        } else if (i == NDEC_ - 1) {
            gemm_k3<0><<<760, 256, 0, stream>>>(
                ff1, W2t + (long)i * 65536, b2 + i * 128, x, x, nullptr,
                nullptr, nullptr, 512);
        } else {
            gemm_k3<1><<<760, 256, 0, stream>>>(
                ff1, W2t + (long)i * 65536, b2 + i * 128, x, x, h,
                ln1g + (i + 1) * 128, ln1b + (i + 1) * 128, 512);
        }
    }

    fin_k<<<MR_ / 4, 256, 0, stream>>>(x, encg, encb, finw, finb, t);
    outgemm_k<<<B_, 128, 0, stream>>>(t, outw, outb, out);
}